// Round 2
// baseline (196.127 us; speedup 1.0000x reference)
//
#include <hip/hip_runtime.h>
#include <hip/hip_bf16.h>
#include <math.h>

// Problem constants (from reference)
#define T_ 256
#define B_ 64
#define I_ 1024
#define L_ 2
#define G_ 4
#define H_ 1024
#define R_ 16

typedef __bf16 bf16x8 __attribute__((ext_vector_type(8)));
typedef float floatx4 __attribute__((ext_vector_type(4)));

__device__ inline bf16x8 cvt_bf16x8(float4 a, float4 b) {
    bf16x8 r;
    r[0] = (__bf16)a.x; r[1] = (__bf16)a.y; r[2] = (__bf16)a.z; r[3] = (__bf16)a.w;
    r[4] = (__bf16)b.x; r[5] = (__bf16)b.y; r[6] = (__bf16)b.z; r[7] = (__bf16)b.w;
    return r;
}

// ---------------------------------------------------------------------------
// Kernel 1 (per layer): fused split-K MFMA GEMM (no LDS) + LoRA t-vectors
//   blocks 0..2047  : GEMM role. 1 wave each; 16 N-cols x full M=64, K-chunk 256.
//                     nb = bid & 255 (N block), kb = bid >> 8 (K split; 0-3 x, 4-7 h)
//                     W/x fp32 read direct from global, cvt->bf16 in registers.
//   blocks 2048..2559: t role. one per (which,g,b): t[g,b,r] = dot(v, A[g,r,:])
// ---------------------------------------------------------------------------
__global__ __launch_bounds__(64) void gemm_t_kernel(
    const float* __restrict__ Wx_l,   // [G*H, 1024] fp32
    const float* __restrict__ Wh_l,   // [G*H, 1024] fp32
    const float* __restrict__ x_src,  // [B,1024] fp32 (layer input)
    const float* __restrict__ h_src,  // [B,1024] fp32 (h0[l])
    const float* __restrict__ A_x_l,  // [G,R,1024]
    const float* __restrict__ A_h_l,  // [G,R,1024]
    float* __restrict__ part,         // [8][64][4096] fp32 partials
    float* __restrict__ t_x,          // [G,B,R]
    float* __restrict__ t_h)          // [G,B,R]
{
    const int bid = blockIdx.x;
    const int lane = threadIdx.x;

    if (bid < 2048) {
        // ---------------- GEMM role ----------------
        const int nb = bid & 255;         // 0..255
        const int kb = bid >> 8;          // 0..7
        const float* Wbase = (kb < 4) ? Wx_l : Wh_l;
        const float* Vbase = (kb < 4) ? x_src : h_src;
        const int kofs = (kb & 3) * 256;

        const int c16 = lane & 15;
        const int quad = lane >> 4;       // 0..3
        const int ncol = nb * 16 + c16;

        const float* wrow = Wbase + (size_t)ncol * 1024 + kofs + quad * 8;
        const float* vcol = Vbase + kofs + quad * 8;

        floatx4 acc[4] = {{0.f,0.f,0.f,0.f},{0.f,0.f,0.f,0.f},
                          {0.f,0.f,0.f,0.f},{0.f,0.f,0.f,0.f}};

        #pragma unroll 2
        for (int ks = 0; ks < 8; ++ks) {
            float4 w0 = *(const float4*)(wrow + ks * 32);
            float4 w1 = *(const float4*)(wrow + ks * 32 + 4);
            bf16x8 bfrag = cvt_bf16x8(w0, w1);
            #pragma unroll
            for (int sub = 0; sub < 4; ++sub) {
                const float* vp = vcol + (size_t)(sub * 16 + c16) * 1024 + ks * 32;
                float4 a0 = *(const float4*)(vp);
                float4 a1 = *(const float4*)(vp + 4);
                bf16x8 afrag = cvt_bf16x8(a0, a1);
                acc[sub] = __builtin_amdgcn_mfma_f32_16x16x32_bf16(afrag, bfrag, acc[sub], 0, 0, 0);
            }
        }

        float* pdst = part + (size_t)kb * 64 * 4096;
        #pragma unroll
        for (int sub = 0; sub < 4; ++sub) {
            #pragma unroll
            for (int r = 0; r < 4; ++r) {
                int m = sub * 16 + quad * 4 + r;   // batch index
                pdst[(size_t)m * 4096 + ncol] = acc[sub][r];
            }
        }
    } else {
        // ---------------- t role ----------------
        // tb in [0,512): which = tb>>8, g = (tb>>6)&3, b = tb&63
        const int tb = bid - 2048;
        const int which = tb >> 8;
        const int g = (tb >> 6) & 3;
        const int b = tb & 63;
        const float* v = (which ? h_src : x_src) + (size_t)b * 1024;
        const float* Abase = (which ? A_h_l : A_x_l) + (size_t)g * R_ * 1024;
        float* tdst = (which ? t_h : t_x) + (size_t)(g * B_ + b) * R_;

        // load v into registers: 16 floats per lane (v[lane + 64*i])
        float vreg[16];
        #pragma unroll
        for (int i = 0; i < 16; ++i) vreg[i] = v[lane + 64 * i];

        for (int r = 0; r < R_; ++r) {
            const float* a = Abase + (size_t)r * 1024;
            float s = 0.f;
            #pragma unroll
            for (int i = 0; i < 16; ++i) s += vreg[i] * a[lane + 64 * i];
            #pragma unroll
            for (int off = 32; off > 0; off >>= 1) s += __shfl_down(s, off);
            if (lane == 0) tdst[r] = s;
        }
    }
}

// ---------------------------------------------------------------------------
// Kernel 2 (per layer): reduce partials + bias + LoRA + activations
// ---------------------------------------------------------------------------
__global__ __launch_bounds__(256) void cell_kernel(
    const float* __restrict__ part,   // [8][64][4096]
    const float* __restrict__ bx_l,   // [G,H]
    const float* __restrict__ bh_l,   // [G,H]
    const float* __restrict__ Bx_l,   // [G,H,R]
    const float* __restrict__ Bh_l,   // [G,H,R]
    const float* __restrict__ t_x,    // [G,B,R]
    const float* __restrict__ t_h,    // [G,B,R]
    const float* __restrict__ c0_l,   // [B,H]
    float* __restrict__ h_out,        // [B,H]
    float* __restrict__ c_out,        // [B,H]
    float* __restrict__ out_final)    // [B,H] or nullptr
{
    int idx = blockIdx.x * 256 + threadIdx.x;   // 0..65535
    int b = idx >> 10;
    int h = idx & 1023;

    float pre[4];
    #pragma unroll
    for (int g = 0; g < 4; ++g) {
        int n = g * 1024 + h;
        float s = bx_l[n] + bh_l[n];
        #pragma unroll
        for (int kk = 0; kk < 8; ++kk)
            s += part[(size_t)kk * 262144 + (size_t)b * 4096 + n];
        const float4* Bx4 = (const float4*)(Bx_l + (size_t)n * 16);
        const float4* Bh4 = (const float4*)(Bh_l + (size_t)n * 16);
        const float4* tx4 = (const float4*)(t_x + (size_t)(g * 64 + b) * 16);
        const float4* th4 = (const float4*)(t_h + (size_t)(g * 64 + b) * 16);
        #pragma unroll
        for (int q = 0; q < 4; ++q) {
            float4 bx = Bx4[q], tx = tx4[q];
            s += bx.x * tx.x + bx.y * tx.y + bx.z * tx.z + bx.w * tx.w;
            float4 bh = Bh4[q], th = th4[q];
            s += bh.x * th.x + bh.y * th.y + bh.z * th.z + bh.w * th.w;
        }
        pre[g] = s;
    }

    float it = 1.f / (1.f + __expf(-pre[0]));
    float ft = 1.f / (1.f + __expf(-pre[1]));
    float gt = tanhf(pre[2]);
    float ot = 1.f / (1.f + __expf(-pre[3]));
    float c = ft * c0_l[idx] + it * gt;
    float hn = ot * tanhf(c);

    h_out[idx] = hn;
    c_out[idx] = c;
    if (out_final) out_final[idx] = hn;
}

// ---------------------------------------------------------------------------
extern "C" void kernel_launch(void* const* d_in, const int* in_sizes, int n_in,
                              void* d_out, int out_size, void* d_ws, size_t ws_size,
                              hipStream_t stream) {
    const float* input_seq = (const float*)d_in[0];
    const float* h0  = (const float*)d_in[1];
    const float* c0  = (const float*)d_in[2];
    const float* W_x = (const float*)d_in[3];
    const float* W_h = (const float*)d_in[4];
    const float* b_x = (const float*)d_in[5];
    const float* b_h = (const float*)d_in[6];
    const float* A_x = (const float*)d_in[7];
    const float* B_x = (const float*)d_in[8];
    const float* A_h = (const float*)d_in[9];
    const float* B_h = (const float*)d_in[10];

    float* out = (float*)d_out;                 // [B,H]
    float* h_t = out + B_ * H_;                 // [L,B,H]
    float* c_t = h_t + L_ * B_ * H_;            // [L,B,H]

    // ws layout: t_x (16KB) | t_h (16KB) | pad to 64KB | part (8MB)
    char* ws = (char*)d_ws;
    float* t_x = (float*)ws;
    float* t_h = t_x + G_ * B_ * R_;
    float* part = (float*)(ws + 64 * 1024);     // [8][64][4096] fp32 = 8 MB

    const float* x_last = input_seq + (size_t)(T_ - 1) * B_ * I_;

    for (int l = 0; l < L_; ++l) {
        const float* x_src = (l == 0) ? x_last : (h_t + (size_t)(l - 1) * B_ * H_);
        const float* h_src = h0 + (size_t)l * B_ * H_;

        gemm_t_kernel<<<2560, 64, 0, stream>>>(
            W_x + (size_t)l * G_ * H_ * I_,
            W_h + (size_t)l * G_ * H_ * H_,
            x_src, h_src,
            A_x + (size_t)l * G_ * R_ * I_,
            A_h + (size_t)l * G_ * R_ * H_,
            part, t_x, t_h);

        cell_kernel<<<256, 256, 0, stream>>>(
            part,
            b_x + (size_t)l * G_ * H_, b_h + (size_t)l * G_ * H_,
            B_x + (size_t)l * G_ * H_ * R_, B_h + (size_t)l * G_ * H_ * R_,
            t_x, t_h,
            c0 + (size_t)l * B_ * H_,
            h_t + (size_t)l * B_ * H_, c_t + (size_t)l * B_ * H_,
            (l == L_ - 1) ? out : nullptr);
    }
}